// Round 1
// 102.396 us; speedup vs baseline: 1.0126x; 1.0126x over previous
//
#include <hip/hip_runtime.h>
#include <cstddef>

#define Bq 16
#define TEq 128
#define TDq 128
#define Hq 256

#define kC2  2.8853900817779268f  /* 2*log2(e) */
#define kL2E 1.4426950408889634f

static __device__ __forceinline__ float fast_rcp(float x) {
#if __has_builtin(__builtin_amdgcn_rcpf)
    return __builtin_amdgcn_rcpf(x);
#else
    return 1.0f / x;
#endif
}

static __device__ __forceinline__ float fast_exp2(float x) {
#if __has_builtin(__builtin_amdgcn_exp2f)
    return __builtin_amdgcn_exp2f(x);
#else
    return exp2f(x);
#endif
}

// ---------------------------------------------------------------------------
// K1: orthogonalize (unchanged — modeled ~2-3 us, not the bottleneck).
// Exclusive cumsum over TE split into 8 chunks of 16 per (b,h).
// ---------------------------------------------------------------------------
__global__ __launch_bounds__(256) void k_ortho(const float* __restrict__ enc,
                                               float* __restrict__ out) {
    const int b = blockIdx.y;
    const int hg = blockIdx.x;            // 0..7
    const int tid = threadIdx.x;
    const int hl = tid & 31;
    const int ck = tid >> 5;              // chunk 0..7 (16 t each)
    const int h = (hg << 5) + hl;

    __shared__ float sums[8][33];

    const float* p = enc + ((size_t)b * TEq + ck * 16) * Hq + h;
    float xs[16];
#pragma unroll
    for (int i = 0; i < 16; ++i) xs[i] = p[(size_t)i * Hq];
    float tot = 0.0f;
#pragma unroll
    for (int i = 0; i < 16; ++i) tot += xs[i];
    sums[ck][hl] = tot;
    __syncthreads();

    float s = 0.0f;
    for (int c = 0; c < ck; ++c) s += sums[c][hl];   // exclusive chunk prefix

    float* q = out + ((size_t)b * TEq + ck * 16) * Hq + h;
#pragma unroll
    for (int i = 0; i < 16; ++i) {
        const float x = xs[i];
        const float r = (x * s) / (x * x);           // exact div, matches ref
        q[(size_t)i * Hq] = x - r * x;
        s += x;
    }
}

// ---------------------------------------------------------------------------
// K2: two GEMMs, NEW 64x64 tile / 256 threads / 4x4 per thread / BK=16.
// vs old 32x64/2x4: LDS bytes per FMA 3.0 -> 2.0, and next-tile global loads
// are issued BEFORE the 16-k compute (latency hidden under ~512 cy of FMA)
// instead of right before the ds_write barrier (latency exposed).
// Grid (4,32,2) = 256 blocks = 1 block/CU.
// ---------------------------------------------------------------------------
__global__ __launch_bounds__(256) void k_gemm2(const float* __restrict__ A0,
                                               const float* __restrict__ A1,
                                               const float* __restrict__ W0,
                                               const float* __restrict__ W1,
                                               float* __restrict__ Cw,
                                               float* __restrict__ Cu) {
    const int z = blockIdx.z;
    const float* __restrict__ A = z ? A1 : A0;
    const float* __restrict__ W = z ? W1 : W0;
    float* __restrict__ C = z ? Cu : Cw;
    const float scale = z ? 1.0f : kC2;

    const int bm = blockIdx.y * 64;
    const int bn = blockIdx.x * 64;

    __shared__ float sA[16][68];   // [k][m] (+4 pad)
    __shared__ float sB[16][64];   // [k][n]

    const int tid = threadIdx.x;
    const int tx = tid & 15;             // n: 4 cols each
    const int ty = tid >> 4;             // m: 4 rows each (0..15)
    const int arow = tid >> 2;           // 0..63
    const int akcol = (tid & 3) << 2;    // 0,4,8,12
    const int brow = tid >> 4;           // 0..15
    const int bcol = (tid & 15) << 2;    // 0..60

    const float* pa = A + (size_t)(bm + arow) * Hq + akcol;
    const float* pb = W + (size_t)brow * Hq + bn + bcol;

    float4 av = *(const float4*)pa;      // prefetch tile 0
    float4 bv = *(const float4*)pb;

    float acc[4][4] = {};

    for (int k0 = 0; k0 < Hq; k0 += 16) {
        __syncthreads();                 // LDS free from previous compute
        sA[akcol + 0][arow] = av.x;
        sA[akcol + 1][arow] = av.y;
        sA[akcol + 2][arow] = av.z;
        sA[akcol + 3][arow] = av.w;
        *(float4*)&sB[brow][bcol] = bv;
        __syncthreads();
        if (k0 + 16 < Hq) {              // issue next-tile loads EARLY
            av = *(const float4*)(pa + k0 + 16);
            bv = *(const float4*)(pb + (size_t)(k0 + 16) * Hq);
        }
#pragma unroll
        for (int k = 0; k < 16; ++k) {
            const float4 a4 = *(const float4*)&sA[k][ty << 2];  // broadcast
            const float4 b4 = *(const float4*)&sB[k][tx << 2];
            acc[0][0] = fmaf(a4.x, b4.x, acc[0][0]);
            acc[0][1] = fmaf(a4.x, b4.y, acc[0][1]);
            acc[0][2] = fmaf(a4.x, b4.z, acc[0][2]);
            acc[0][3] = fmaf(a4.x, b4.w, acc[0][3]);
            acc[1][0] = fmaf(a4.y, b4.x, acc[1][0]);
            acc[1][1] = fmaf(a4.y, b4.y, acc[1][1]);
            acc[1][2] = fmaf(a4.y, b4.z, acc[1][2]);
            acc[1][3] = fmaf(a4.y, b4.w, acc[1][3]);
            acc[2][0] = fmaf(a4.z, b4.x, acc[2][0]);
            acc[2][1] = fmaf(a4.z, b4.y, acc[2][1]);
            acc[2][2] = fmaf(a4.z, b4.z, acc[2][2]);
            acc[2][3] = fmaf(a4.z, b4.w, acc[2][3]);
            acc[3][0] = fmaf(a4.w, b4.x, acc[3][0]);
            acc[3][1] = fmaf(a4.w, b4.y, acc[3][1]);
            acc[3][2] = fmaf(a4.w, b4.z, acc[3][2]);
            acc[3][3] = fmaf(a4.w, b4.w, acc[3][3]);
        }
    }
#pragma unroll
    for (int i = 0; i < 4; ++i) {
        float4 o;
        o.x = acc[i][0] * scale;
        o.y = acc[i][1] * scale;
        o.z = acc[i][2] * scale;
        o.w = acc[i][3] * scale;
        *(float4*)(C + (size_t)(bm + (ty << 2) + i) * Hq + bn + (tx << 2)) = o;
    }
}

// ---------------------------------------------------------------------------
// K3: energies + softmax + context. NEW vs R2-best:
//  - 4 decoder rows per block (was 2): was/enc_o re-read traffic halved
//    (256 MB -> 128 MB), per was-element 4 tanh chains -> more trans ILP.
//  - XCD-aware block decode: each XCD owns exactly 2 b's, so its working set
//    (was[b]+enc_o[b]+uah[b] for 2 b) = 768 KB — fully L2-resident instead of
//    thrashing 6 MB across the 4 MiB per-XCD L2.
// Grid 512 blocks x 256 thr = 2 waves/SIMD. Wave w covers e-quarter w and all
// 4 d's per was-row read. tanh(z) = 1 - 2/(exp2(C2*z)+1); energy = Vsum -
// 2*sum(v*r). was pre-scaled by C2 (K2 epilogue); uah scaled at LDS load.
// ---------------------------------------------------------------------------
__global__ __launch_bounds__(256) void k_attn(const float* __restrict__ was,
                                              const float* __restrict__ uah,
                                              const float* __restrict__ enc_o,
                                              const float* __restrict__ Va,
                                              float* __restrict__ c_out,
                                              float* __restrict__ e_out) {
    // XCD-aware decode (blocks dispatched round-robin over 8 XCDs):
    const int lin = blockIdx.y * gridDim.x + blockIdx.x;   // dispatch order
    const int xcd = lin & 7;
    const int idx = lin >> 3;                 // 0..63
    const int b = (xcd << 1) | (idx >> 5);    // 2 b's per XCD
    const int d0 = (idx & 31) << 2;           // 4 decoder rows per block

    __shared__ float uahs[4][Hq];
    __shared__ float Vs[Hq];
    __shared__ float wts[4][TEq];   // energies, then softmax weights

    const int tid = threadIdx.x;
    const int w = tid >> 6;         // wave 0..3 -> e-quarter / own d in softmax
    const int lane = tid & 63;

    Vs[tid] = Va[tid];
#pragma unroll
    for (int j = 0; j < 4; ++j)
        uahs[j][tid] = uah[((size_t)b * TDq + d0 + j) * Hq + tid] * kC2;
    __syncthreads();

    const int g = lane >> 4;        // sub-group 0..3
    const int ll = lane & 15;

    // Vsum (redundant per wave)
    float vs = Vs[lane] + Vs[lane + 64] + Vs[lane + 128] + Vs[lane + 192];
#pragma unroll
    for (int m = 1; m <= 32; m <<= 1) vs += __shfl_xor(vs, m);

    // preload u/v fragments for all 4 d's: h = c*64 + ll*4 + i
    float4 u0[4], u1[4], u2[4], u3[4], vr[4];
#pragma unroll
    for (int c = 0; c < 4; ++c) {
        u0[c] = *(const float4*)&uahs[0][c * 64 + (ll << 2)];
        u1[c] = *(const float4*)&uahs[1][c * 64 + (ll << 2)];
        u2[c] = *(const float4*)&uahs[2][c * 64 + (ll << 2)];
        u3[c] = *(const float4*)&uahs[3][c * 64 + (ll << 2)];
        vr[c] = *(const float4*)&Vs[c * 64 + (ll << 2)];
    }

    const float* wasb = was + (size_t)b * TEq * Hq;

    for (int ei = 0; ei < 8; ++ei) {
        const int e = (w << 5) + (g << 3) + ei;   // e-quarter w, group g
        const float* wp = wasb + (size_t)e * Hq + (ll << 2);
        float a0 = 0.0f, a1 = 0.0f, a2 = 0.0f, a3 = 0.0f;
#pragma unroll
        for (int c = 0; c < 4; ++c) {
            const float4 wv = *(const float4*)(wp + c * 64);
            const float wf[4] = {wv.x, wv.y, wv.z, wv.w};
            const float f0[4] = {u0[c].x, u0[c].y, u0[c].z, u0[c].w};
            const float f1[4] = {u1[c].x, u1[c].y, u1[c].z, u1[c].w};
            const float f2[4] = {u2[c].x, u2[c].y, u2[c].z, u2[c].w};
            const float f3[4] = {u3[c].x, u3[c].y, u3[c].z, u3[c].w};
            const float vf[4] = {vr[c].x, vr[c].y, vr[c].z, vr[c].w};
#pragma unroll
            for (int i = 0; i < 4; ++i) {
                const float t0 = fast_exp2(wf[i] + f0[i]);
                a0 = fmaf(vf[i], fast_rcp(t0 + 1.0f), a0);
                const float t1 = fast_exp2(wf[i] + f1[i]);
                a1 = fmaf(vf[i], fast_rcp(t1 + 1.0f), a1);
                const float t2 = fast_exp2(wf[i] + f2[i]);
                a2 = fmaf(vf[i], fast_rcp(t2 + 1.0f), a2);
                const float t3 = fast_exp2(wf[i] + f3[i]);
                a3 = fmaf(vf[i], fast_rcp(t3 + 1.0f), a3);
            }
        }
#pragma unroll
        for (int m = 1; m <= 8; m <<= 1) {
            a0 += __shfl_xor(a0, m);
            a1 += __shfl_xor(a1, m);
            a2 += __shfl_xor(a2, m);
            a3 += __shfl_xor(a3, m);
        }
        if (ll == 0) {
            wts[0][e] = vs - 2.0f * a0;
            wts[1][e] = vs - 2.0f * a1;
            wts[2][e] = vs - 2.0f * a2;
            wts[3][e] = vs - 2.0f * a3;
        }
    }
    __syncthreads();

    // softmax: wave w handles d = d0 + w (all 4 waves active now)
    {
        const float v0 = wts[w][lane];
        const float v1 = wts[w][lane + 64];
        float mx = fmaxf(v0, v1);
#pragma unroll
        for (int m = 1; m <= 32; m <<= 1) mx = fmaxf(mx, __shfl_xor(mx, m));
        const float e0 = fast_exp2((v0 - mx) * kL2E);
        const float e1 = fast_exp2((v1 - mx) * kL2E);
        float sm = e0 + e1;
#pragma unroll
        for (int m = 1; m <= 32; m <<= 1) sm += __shfl_xor(sm, m);
        const float inv = fast_rcp(sm);
        const float w0 = e0 * inv;
        const float w1 = e1 * inv;
        wts[w][lane] = w0;
        wts[w][lane + 64] = w1;
        const size_t eb = ((size_t)b * TDq + d0 + w) * TEq;
        e_out[eb + lane] = w0;
        e_out[eb + lane + 64] = w1;
    }
    __syncthreads();

    // context: c[b,d0+j,h=tid] = sum_e wts[j][e] * enc_o[b,e,h]
    float a0 = 0.0f, a1 = 0.0f, a2 = 0.0f, a3 = 0.0f;
    const float* ep = enc_o + (size_t)b * TEq * Hq + tid;
#pragma unroll 4
    for (int e4 = 0; e4 < TEq; e4 += 4) {
        const float4 w0v = *(const float4*)&wts[0][e4];
        const float4 w1v = *(const float4*)&wts[1][e4];
        const float4 w2v = *(const float4*)&wts[2][e4];
        const float4 w3v = *(const float4*)&wts[3][e4];
        const float x0 = ep[(size_t)(e4 + 0) * Hq];
        const float x1 = ep[(size_t)(e4 + 1) * Hq];
        const float x2 = ep[(size_t)(e4 + 2) * Hq];
        const float x3 = ep[(size_t)(e4 + 3) * Hq];
        a0 = fmaf(w0v.x, x0, a0); a1 = fmaf(w1v.x, x0, a1);
        a2 = fmaf(w2v.x, x0, a2); a3 = fmaf(w3v.x, x0, a3);
        a0 = fmaf(w0v.y, x1, a0); a1 = fmaf(w1v.y, x1, a1);
        a2 = fmaf(w2v.y, x1, a2); a3 = fmaf(w3v.y, x1, a3);
        a0 = fmaf(w0v.z, x2, a0); a1 = fmaf(w1v.z, x2, a1);
        a2 = fmaf(w2v.z, x2, a2); a3 = fmaf(w3v.z, x2, a3);
        a0 = fmaf(w0v.w, x3, a0); a1 = fmaf(w1v.w, x3, a1);
        a2 = fmaf(w2v.w, x3, a2); a3 = fmaf(w3v.w, x3, a3);
    }
    const size_t cb = ((size_t)b * TDq + d0) * Hq + tid;
    c_out[cb] = a0;
    c_out[cb + Hq] = a1;
    c_out[cb + 2 * (size_t)Hq] = a2;
    c_out[cb + 3 * (size_t)Hq] = a3;
}

extern "C" void kernel_launch(void* const* d_in, const int* in_sizes, int n_in,
                              void* d_out, int out_size, void* d_ws, size_t ws_size,
                              hipStream_t stream) {
    const float* enc = (const float*)d_in[0];   // [16,128,256]
    const float* dec = (const float*)d_in[1];   // [16,128,256]
    const float* Wa  = (const float*)d_in[2];   // [256,256]
    const float* Ua  = (const float*)d_in[3];   // [256,256]
    const float* Va  = (const float*)d_in[4];   // [256,1]

    float* c_out = (float*)d_out;                        // [16,128,256]
    float* e_out = c_out + (size_t)Bq * TDq * Hq;        // [16,128,128]

    float* enc_o = (float*)d_ws;                         // 2 MB
    float* wasb  = enc_o + (size_t)Bq * TEq * Hq;        // 2 MB (pre-scaled by 2*log2e)
    float* uahb  = wasb + (size_t)Bq * TEq * Hq;         // 2 MB

    k_ortho<<<dim3(Hq / 32, Bq), dim3(256), 0, stream>>>(enc, enc_o);
    k_gemm2<<<dim3(Hq / 64, (Bq * TEq) / 64, 2), dim3(256), 0, stream>>>(
        enc_o, dec, Wa, Ua, wasb, uahb);
    k_attn<<<dim3(TDq / 4, Bq), dim3(256), 0, stream>>>(
        wasb, uahb, enc_o, Va, c_out, e_out);
}